// Round 1
// 475.879 us; speedup vs baseline: 1.0174x; 1.0174x over previous
//
#include <hip/hip_runtime.h>
#include <math.h>

#define BH 131072  // B*H = 256*512

typedef float f4v __attribute__((ext_vector_type(4)));

// ---------------- Kernel A: six projections ----------------
// out[b, n] = sum_d x[b,d] * Wstack[n, d],  n in [0, 3072)
// mat = n>>9 selects W_q..W_o; mats 3,4,5 get bias + sigmoid.
// Tiles: BM=64 (batch), BN=64 (n), BK=16. 256 threads, 4x4 micro-tile.
__global__ __launch_bounds__(256) void proj_gemm(
    const float* __restrict__ x,
    const float* __restrict__ Wq, const float* __restrict__ Wk,
    const float* __restrict__ Wv, const float* __restrict__ Wi,
    const float* __restrict__ Wf, const float* __restrict__ Wo,
    const float* __restrict__ bi, const float* __restrict__ bf,
    const float* __restrict__ bo,
    float* __restrict__ ws)
{
    __shared__ float As[16][64];  // [k][m]
    __shared__ float Bs[16][64];  // [k][n]

    const int t  = threadIdx.x;
    const int tx = t & 15;        // n-dir
    const int ty = t >> 4;        // m-dir
    const int n0 = blockIdx.x * 64;
    const int m0 = blockIdx.y * 64;
    const int mat = n0 >> 9;      // 64 | 512, so a tile never spans matrices
    const int hn0 = n0 & 511;

    const float* W;
    switch (mat) {
        case 0: W = Wq; break; case 1: W = Wk; break; case 2: W = Wv; break;
        case 3: W = Wi; break; case 4: W = Wf; break; default: W = Wo; break;
    }

    const int lr = t >> 2;         // 0..63 : row within tile
    const int lk = (t & 3) * 4;    // 0,4,8,12 : k within chunk
    const float* xg = &x[(m0 + lr) * 512 + lk];
    const float* wg = &W[(hn0 + lr) * 512 + lk];

    float4 xa = *(const float4*)xg;   // prefetch chunk 0
    float4 wa = *(const float4*)wg;

    float acc[4][4];
#pragma unroll
    for (int i = 0; i < 4; i++)
#pragma unroll
        for (int j = 0; j < 4; j++) acc[i][j] = 0.f;

    for (int k0 = 0; k0 < 512; k0 += 16) {
        As[lk + 0][lr] = xa.x; As[lk + 1][lr] = xa.y;
        As[lk + 2][lr] = xa.z; As[lk + 3][lr] = xa.w;
        Bs[lk + 0][lr] = wa.x; Bs[lk + 1][lr] = wa.y;
        Bs[lk + 2][lr] = wa.z; Bs[lk + 3][lr] = wa.w;
        __syncthreads();
        if (k0 + 16 < 512) {  // register prefetch of next chunk (hide HBM latency)
            xa = *(const float4*)(xg + k0 + 16);
            wa = *(const float4*)(wg + k0 + 16);
        }
#pragma unroll
        for (int kk = 0; kk < 16; kk++) {
            float4 a4 = *(const float4*)&As[kk][ty * 4];
            float4 b4 = *(const float4*)&Bs[kk][tx * 4];
            float a[4] = {a4.x, a4.y, a4.z, a4.w};
            float b[4] = {b4.x, b4.y, b4.z, b4.w};
#pragma unroll
            for (int i = 0; i < 4; i++)
#pragma unroll
                for (int j = 0; j < 4; j++) acc[i][j] += a[i] * b[j];
        }
        __syncthreads();
    }

    // Epilogue: bias + sigmoid for i/f/o, vectorized store to workspace.
    const float* bias = (mat == 3) ? bi : (mat == 4) ? bf : (mat == 5) ? bo : nullptr;
    float bv[4] = {0.f, 0.f, 0.f, 0.f};
    if (bias) {
#pragma unroll
        for (int j = 0; j < 4; j++) bv[j] = bias[hn0 + tx * 4 + j];
    }
#pragma unroll
    for (int i = 0; i < 4; i++) {
        const int b = m0 + ty * 4 + i;
        float4 o;
        float r[4];
#pragma unroll
        for (int j = 0; j < 4; j++) {
            float vv = acc[i][j];
            if (bias) vv = 1.f / (1.f + expf(-(vv + bv[j])));
            r[j] = vv;
        }
        o.x = r[0]; o.y = r[1]; o.z = r[2]; o.w = r[3];
        *(float4*)&ws[(size_t)mat * BH + b * 512 + hn0 + tx * 4] = o;
    }
}

// ---------------- Kernel B: fused state update + readout ----------------
// C_t[b,i,:] = f[b,i]*C_prev[b,i,:] + (i[b,i]*k[b,i])*v[b,:]
// h[b,i]     = o[b,i] * tanh( dot(C_t[b,i,:], q[b,:]) )
// One wave per row, TWO rows in flight per wave.
// v,q AND the block's 32 gate triples (f, i*k, o) staged in LDS once —
// removes 24 uniform global loads per wave from the critical path.
// Explicit 1-deep prefetch pipeline: next iteration's C loads issue before
// the current iteration's FMA/store/reduce, so the 12-deep bpermute reduce
// chain + tanh overlap with HBM latency.
// Nontemporal hints on the 512 MB C streams (no reuse; keep L2 for v/q/ws).
#define ROWS 32
__global__ __launch_bounds__(256) void update_kernel(
    const float* __restrict__ Cprev,
    const float* __restrict__ ws,
    float* __restrict__ hout,
    float* __restrict__ Cout)
{
    const int rblk = blockIdx.x;   // 0..15  (adjacent blocks share b -> L2 reuse of v/q)
    const int b    = blockIdx.y;   // 0..255

    __shared__ float vq[1024];     // v[0..511], q[512..1023]
    __shared__ float gf[ROWS];     // f gate
    __shared__ float gik[ROWS];    // i*k
    __shared__ float go[ROWS];     // o gate

    const float* qv = ws + 0 * (size_t)BH + b * 512;
    const float* kv = ws + 1 * (size_t)BH + b * 512;
    const float* vv = ws + 2 * (size_t)BH + b * 512;
    const float* ig = ws + 3 * (size_t)BH + b * 512;
    const float* fg = ws + 4 * (size_t)BH + b * 512;
    const float* og = ws + 5 * (size_t)BH + b * 512;

    const int t = threadIdx.x;
    ((float4*)vq)[t] = (t < 128) ? ((const float4*)vv)[t]
                                 : ((const float4*)qv)[t - 128];
    if (t < ROWS) {
        const int r = rblk * ROWS + t;
        gf[t]  = fg[r];
        gik[t] = ig[r] * kv[r];
        go[t]  = og[r];
    }
    __syncthreads();

    const int wave = t >> 6;
    const int lane = t & 63;

    const f4v v0 = ((const f4v*)vq)[lane];
    const f4v v1 = ((const f4v*)vq)[64 + lane];
    const f4v q0 = ((const f4v*)(vq + 512))[lane];
    const f4v q1 = ((const f4v*)(vq + 512))[64 + lane];

    // Base of this block's 32-row slab; row r occupies 128 float4 chunks.
    const f4v* cin = (const f4v*)(Cprev + ((size_t)b * 512 + rblk * ROWS) * 512);
    f4v*       cou = (f4v*)(Cout + ((size_t)b * 512 + rblk * ROWS) * 512);

    // Prologue: loads for iteration 0 (rows wave, wave+4).
    f4v a0 = __builtin_nontemporal_load(cin + (size_t)wave * 128 + lane);
    f4v a1 = __builtin_nontemporal_load(cin + (size_t)wave * 128 + 64 + lane);
    f4v b0 = __builtin_nontemporal_load(cin + (size_t)(wave + 4) * 128 + lane);
    f4v b1 = __builtin_nontemporal_load(cin + (size_t)(wave + 4) * 128 + 64 + lane);

    // 4 iterations, 2 rows per iteration per wave (local rows lA and lA+4)
#pragma unroll
    for (int it = 0; it < 4; it++) {
        const int lA = wave + it * 8;
        const int lB = lA + 4;

        // Prefetch next iteration's C rows (static guard after unroll).
        f4v p0, p1, p2, p3;
        if (it < 3) {
            p0 = __builtin_nontemporal_load(cin + (size_t)(lA + 8) * 128 + lane);
            p1 = __builtin_nontemporal_load(cin + (size_t)(lA + 8) * 128 + 64 + lane);
            p2 = __builtin_nontemporal_load(cin + (size_t)(lB + 8) * 128 + lane);
            p3 = __builtin_nontemporal_load(cin + (size_t)(lB + 8) * 128 + 64 + lane);
        }

        // Gates from LDS (uniform broadcast, conflict-free).
        const float fA  = gf[lA];
        const float ikA = gik[lA];
        const float oA  = go[lA];
        const float fB  = gf[lB];
        const float ikB = gik[lB];
        const float oB  = go[lB];

        f4v nA0 = fA * a0 + ikA * v0;
        f4v nA1 = fA * a1 + ikA * v1;
        f4v nB0 = fB * b0 + ikB * v0;
        f4v nB1 = fB * b1 + ikB * v1;

        __builtin_nontemporal_store(nA0, cou + (size_t)lA * 128 + lane);
        __builtin_nontemporal_store(nA1, cou + (size_t)lA * 128 + 64 + lane);
        __builtin_nontemporal_store(nB0, cou + (size_t)lB * 128 + lane);
        __builtin_nontemporal_store(nB1, cou + (size_t)lB * 128 + 64 + lane);

        f4v pA = nA0 * q0 + nA1 * q1;
        f4v pB = nB0 * q0 + nB1 * q1;
        float dA = pA.x + pA.y + pA.z + pA.w;
        float dB = pB.x + pB.y + pB.z + pB.w;

        // two independent shuffle-reduce chains, interleaved
#pragma unroll
        for (int off = 32; off > 0; off >>= 1) {
            dA += __shfl_down(dA, off, 64);
            dB += __shfl_down(dB, off, 64);
        }

        if (lane == 0) {
            hout[b * 512 + rblk * ROWS + lA] = oA * tanhf(dA);
            hout[b * 512 + rblk * ROWS + lB] = oB * tanhf(dB);
        }

        // Rotate pipeline registers.
        a0 = p0; a1 = p1; b0 = p2; b1 = p3;
    }
}

extern "C" void kernel_launch(void* const* d_in, const int* in_sizes, int n_in,
                              void* d_out, int out_size, void* d_ws, size_t ws_size,
                              hipStream_t stream) {
    const float* x     = (const float*)d_in[0];
    // d_in[1] = h_prev (unused by the reference)
    const float* Cprev = (const float*)d_in[2];
    const float* Wq    = (const float*)d_in[3];
    const float* Wk    = (const float*)d_in[4];
    const float* Wv    = (const float*)d_in[5];
    const float* Wi    = (const float*)d_in[6];
    const float* Wf    = (const float*)d_in[7];
    const float* Wo    = (const float*)d_in[8];
    const float* bi    = (const float*)d_in[9];
    const float* bf    = (const float*)d_in[10];
    const float* bo    = (const float*)d_in[11];

    float* ws   = (float*)d_ws;
    float* hout = (float*)d_out;          // h_t: BH floats
    float* Cout = hout + BH;              // C_t: B*H*H floats

    proj_gemm<<<dim3(48, 4), 256, 0, stream>>>(x, Wq, Wk, Wv, Wi, Wf, Wo,
                                               bi, bf, bo, ws);
    update_kernel<<<dim3(16, 256), 256, 0, stream>>>(Cprev, ws, hout, Cout);
}

// Round 2
// 475.300 us; speedup vs baseline: 1.0187x; 1.0012x over previous
//
#include <hip/hip_runtime.h>
#include <math.h>

#define BH 131072  // B*H = 256*512

typedef float f4v __attribute__((ext_vector_type(4)));
typedef float f2v __attribute__((ext_vector_type(2)));

// ---------------- Kernel A: six projections ----------------
// out[b, n] = sum_d x[b,d] * Wstack[n, d],  n in [0, 3072)
// mat = n>>9 selects W_q..W_o; mats 3,4,5 get bias + sigmoid.
// Tiles: BM=32 (batch), BN=64 (n), BK=16. 256 threads, 2x4 micro-tile.
// grid (48, 8) = 384 blocks: 2x the wave-parallelism of the old 64x64/192-block
// version (which left the GPU at <1 wave/SIMD and latency-exposed).
__global__ __launch_bounds__(256) void proj_gemm(
    const float* __restrict__ x,
    const float* __restrict__ Wq, const float* __restrict__ Wk,
    const float* __restrict__ Wv, const float* __restrict__ Wi,
    const float* __restrict__ Wf, const float* __restrict__ Wo,
    const float* __restrict__ bi, const float* __restrict__ bf,
    const float* __restrict__ bo,
    float* __restrict__ ws)
{
    __shared__ float As[16][32];  // [k][m]
    __shared__ float Bs[16][64];  // [k][n]

    const int t  = threadIdx.x;
    const int tx = t & 15;        // n-dir, 4 cols each
    const int ty = t >> 4;        // m-dir, 2 rows each
    const int n0 = blockIdx.x * 64;
    const int m0 = blockIdx.y * 32;
    const int mat = n0 >> 9;      // tiles never span matrices (64 | 512)
    const int hn0 = n0 & 511;

    const float* W;
    switch (mat) {
        case 0: W = Wq; break; case 1: W = Wk; break; case 2: W = Wv; break;
        case 3: W = Wi; break; case 4: W = Wf; break; default: W = Wo; break;
    }

    // Staging: W-tile 64 rows x 16 k (all 256 threads, float4 each);
    //          x-tile 32 rows x 16 k (threads t<128 only).
    const int wr = t >> 2;          // 0..63
    const int wk = (t & 3) * 4;     // 0,4,8,12
    const float* wg = &W[(hn0 + wr) * 512 + wk];
    const float* xg = &x[(m0 + (t >> 2)) * 512 + ((t & 3) * 4)]; // valid for t<128

    float4 wa = *(const float4*)wg;     // prefetch chunk 0
    float4 xa;
    if (t < 128) xa = *(const float4*)xg;

    float acc[2][4];
#pragma unroll
    for (int i = 0; i < 2; i++)
#pragma unroll
        for (int j = 0; j < 4; j++) acc[i][j] = 0.f;

    for (int k0 = 0; k0 < 512; k0 += 16) {
        if (t < 128) {
            As[wk + 0][wr] = xa.x; As[wk + 1][wr] = xa.y;
            As[wk + 2][wr] = xa.z; As[wk + 3][wr] = xa.w;
        }
        Bs[wk + 0][wr] = wa.x; Bs[wk + 1][wr] = wa.y;
        Bs[wk + 2][wr] = wa.z; Bs[wk + 3][wr] = wa.w;
        __syncthreads();
        if (k0 + 16 < 512) {  // register prefetch of next chunk
            wa = *(const float4*)(wg + k0 + 16);
            if (t < 128) xa = *(const float4*)(xg + k0 + 16);
        }
#pragma unroll
        for (int kk = 0; kk < 16; kk++) {
            f2v a2 = *(const f2v*)&As[kk][ty * 2];
            float4 b4 = *(const float4*)&Bs[kk][tx * 4];
            float a[2] = {a2.x, a2.y};
            float b[4] = {b4.x, b4.y, b4.z, b4.w};
#pragma unroll
            for (int i = 0; i < 2; i++)
#pragma unroll
                for (int j = 0; j < 4; j++) acc[i][j] += a[i] * b[j];
        }
        __syncthreads();
    }

    // Epilogue: bias + sigmoid for i/f/o, vectorized store to workspace.
    const float* bias = (mat == 3) ? bi : (mat == 4) ? bf : (mat == 5) ? bo : nullptr;
    float bv[4] = {0.f, 0.f, 0.f, 0.f};
    if (bias) {
#pragma unroll
        for (int j = 0; j < 4; j++) bv[j] = bias[hn0 + tx * 4 + j];
    }
#pragma unroll
    for (int i = 0; i < 2; i++) {
        const int b = m0 + ty * 2 + i;
        float4 o;
        float r[4];
#pragma unroll
        for (int j = 0; j < 4; j++) {
            float vv = acc[i][j];
            if (bias) vv = 1.f / (1.f + expf(-(vv + bv[j])));
            r[j] = vv;
        }
        o.x = r[0]; o.y = r[1]; o.z = r[2]; o.w = r[3];
        *(float4*)&ws[(size_t)mat * BH + b * 512 + hn0 + tx * 4] = o;
    }
}

// ---------------- Kernel B: fused state update + readout ----------------
// C_t[b,i,:] = f[b,i]*C_prev[b,i,:] + (i[b,i]*k[b,i])*v[b,:]
// h[b,i]     = o[b,i] * tanh( dot(C_t[b,i,:], q[b,:]) )
// One wave per row, TWO rows in flight per wave.
// Prologue C loads issued BEFORE the v/q/gate LDS staging so the 268 MB
// stream starts immediately (staging no longer serializes block start).
// v,q and the block's 32 gate triples (f, i*k, o) staged in LDS once.
// 1-deep prefetch pipeline: next iteration's C loads issue before the
// current iteration's FMA/store/reduce.
// Nontemporal hints on the 512 MB C streams (no reuse; keep L2 for ws).
#define ROWS 32
__global__ __launch_bounds__(256) void update_kernel(
    const float* __restrict__ Cprev,
    const float* __restrict__ ws,
    float* __restrict__ hout,
    float* __restrict__ Cout)
{
    const int rblk = blockIdx.x;   // 0..15  (adjacent blocks share b -> L2 reuse)
    const int b    = blockIdx.y;   // 0..255

    __shared__ float vq[1024];     // v[0..511], q[512..1023]
    __shared__ float gf[ROWS];     // f gate
    __shared__ float gik[ROWS];    // i*k
    __shared__ float go[ROWS];     // o gate

    const int t = threadIdx.x;
    const int wave = t >> 6;
    const int lane = t & 63;

    // Base of this block's 32-row slab; row r occupies 128 float4 chunks.
    const f4v* cin = (const f4v*)(Cprev + ((size_t)b * 512 + rblk * ROWS) * 512);
    f4v*       cou = (f4v*)(Cout + ((size_t)b * 512 + rblk * ROWS) * 512);

    // Issue iteration-0 C loads FIRST (rows wave, wave+4) — independent of LDS.
    f4v a0 = __builtin_nontemporal_load(cin + (size_t)wave * 128 + lane);
    f4v a1 = __builtin_nontemporal_load(cin + (size_t)wave * 128 + 64 + lane);
    f4v b0 = __builtin_nontemporal_load(cin + (size_t)(wave + 4) * 128 + lane);
    f4v b1 = __builtin_nontemporal_load(cin + (size_t)(wave + 4) * 128 + 64 + lane);

    const float* qv = ws + 0 * (size_t)BH + b * 512;
    const float* kv = ws + 1 * (size_t)BH + b * 512;
    const float* vv = ws + 2 * (size_t)BH + b * 512;
    const float* ig = ws + 3 * (size_t)BH + b * 512;
    const float* fg = ws + 4 * (size_t)BH + b * 512;
    const float* og = ws + 5 * (size_t)BH + b * 512;

    ((float4*)vq)[t] = (t < 128) ? ((const float4*)vv)[t]
                                 : ((const float4*)qv)[t - 128];
    if (t < ROWS) {
        const int r = rblk * ROWS + t;
        gf[t]  = fg[r];
        gik[t] = ig[r] * kv[r];
        go[t]  = og[r];
    }
    __syncthreads();

    const f4v v0 = ((const f4v*)vq)[lane];
    const f4v v1 = ((const f4v*)vq)[64 + lane];
    const f4v q0 = ((const f4v*)(vq + 512))[lane];
    const f4v q1 = ((const f4v*)(vq + 512))[64 + lane];

    // 4 iterations, 2 rows per iteration per wave (local rows lA and lA+4)
#pragma unroll
    for (int it = 0; it < 4; it++) {
        const int lA = wave + it * 8;
        const int lB = lA + 4;

        // Prefetch next iteration's C rows (static guard after unroll).
        f4v p0, p1, p2, p3;
        if (it < 3) {
            p0 = __builtin_nontemporal_load(cin + (size_t)(lA + 8) * 128 + lane);
            p1 = __builtin_nontemporal_load(cin + (size_t)(lA + 8) * 128 + 64 + lane);
            p2 = __builtin_nontemporal_load(cin + (size_t)(lB + 8) * 128 + lane);
            p3 = __builtin_nontemporal_load(cin + (size_t)(lB + 8) * 128 + 64 + lane);
        }

        // Gates from LDS (uniform broadcast, conflict-free).
        const float fA  = gf[lA];
        const float ikA = gik[lA];
        const float oA  = go[lA];
        const float fB  = gf[lB];
        const float ikB = gik[lB];
        const float oB  = go[lB];

        f4v nA0 = fA * a0 + ikA * v0;
        f4v nA1 = fA * a1 + ikA * v1;
        f4v nB0 = fB * b0 + ikB * v0;
        f4v nB1 = fB * b1 + ikB * v1;

        __builtin_nontemporal_store(nA0, cou + (size_t)lA * 128 + lane);
        __builtin_nontemporal_store(nA1, cou + (size_t)lA * 128 + 64 + lane);
        __builtin_nontemporal_store(nB0, cou + (size_t)lB * 128 + lane);
        __builtin_nontemporal_store(nB1, cou + (size_t)lB * 128 + 64 + lane);

        f4v pA = nA0 * q0 + nA1 * q1;
        f4v pB = nB0 * q0 + nB1 * q1;
        float dA = pA.x + pA.y + pA.z + pA.w;
        float dB = pB.x + pB.y + pB.z + pB.w;

        // two independent shuffle-reduce chains, interleaved
#pragma unroll
        for (int off = 32; off > 0; off >>= 1) {
            dA += __shfl_down(dA, off, 64);
            dB += __shfl_down(dB, off, 64);
        }

        if (lane == 0) {
            hout[b * 512 + rblk * ROWS + lA] = oA * tanhf(dA);
            hout[b * 512 + rblk * ROWS + lB] = oB * tanhf(dB);
        }

        // Rotate pipeline registers.
        a0 = p0; a1 = p1; b0 = p2; b1 = p3;
    }
}

extern "C" void kernel_launch(void* const* d_in, const int* in_sizes, int n_in,
                              void* d_out, int out_size, void* d_ws, size_t ws_size,
                              hipStream_t stream) {
    const float* x     = (const float*)d_in[0];
    // d_in[1] = h_prev (unused by the reference)
    const float* Cprev = (const float*)d_in[2];
    const float* Wq    = (const float*)d_in[3];
    const float* Wk    = (const float*)d_in[4];
    const float* Wv    = (const float*)d_in[5];
    const float* Wi    = (const float*)d_in[6];
    const float* Wf    = (const float*)d_in[7];
    const float* Wo    = (const float*)d_in[8];
    const float* bi    = (const float*)d_in[9];
    const float* bf    = (const float*)d_in[10];
    const float* bo    = (const float*)d_in[11];

    float* ws   = (float*)d_ws;
    float* hout = (float*)d_out;          // h_t: BH floats
    float* Cout = hout + BH;              // C_t: B*H*H floats

    proj_gemm<<<dim3(48, 8), 256, 0, stream>>>(x, Wq, Wk, Wv, Wi, Wf, Wo,
                                               bi, bf, bo, ws);
    update_kernel<<<dim3(16, 256), 256, 0, stream>>>(Cprev, ws, hout, Cout);
}